// Round 15
// baseline (221.735 us; speedup 1.0000x reference)
//
#include <hip/hip_runtime.h>
#include <hip/hip_bf16.h>
#include <stdint.h>

// Problem constants (B=1). I/O dtype: fp32. Internals bf16 (MFMA path).
#define S_LEN 2048
#define HID   2048
#define NQH   32
#define NKVH  8
#define HD    64
#define QKV_O 3072      // (32 + 2*8) * 64
#define K_COL 2048      // col offset of K block in qkv row
#define V_COL 2560      // col offset of V block in qkv row

typedef unsigned short ushort_t;
typedef __bf16 bf16x8 __attribute__((ext_vector_type(8)));
typedef float  f32x4  __attribute__((ext_vector_type(4)));

#define GLB(p) ((const __attribute__((address_space(1))) void*)(p))
#define LDSP(p) ((__attribute__((address_space(3))) void*)(p))

__device__ __forceinline__ ushort_t f2bf(float f) {
    unsigned int x = __float_as_uint(f);
    unsigned int r = (x + 0x7fffu + ((x >> 16) & 1u)) >> 16;   // RNE
    return (ushort_t)r;
}
__device__ __forceinline__ unsigned int pk_bf16(float a, float b) {
    __hip_bfloat162 h = __float22bfloat162_rn(make_float2(a, b));
    unsigned int r;
    __builtin_memcpy(&r, &h, 4);
    return r;
}
__device__ __forceinline__ void unpack8(float* dst, uint4 u) {
    dst[0] = __uint_as_float(u.x << 16); dst[1] = __uint_as_float(u.x & 0xffff0000u);
    dst[2] = __uint_as_float(u.y << 16); dst[3] = __uint_as_float(u.y & 0xffff0000u);
    dst[4] = __uint_as_float(u.z << 16); dst[5] = __uint_as_float(u.z & 0xffff0000u);
    dst[6] = __uint_as_float(u.w << 16); dst[7] = __uint_as_float(u.w & 0xffff0000u);
}

// ---------------------------------------------------------------------------
// convert3: fp32 -> bf16 for x, w_qkv, w_out (unchanged)
// ---------------------------------------------------------------------------
#define XN8 (S_LEN * HID / 8)          // 524288
#define QN8 (QKV_O * HID / 8)          // 786432
#define ON8 (HID * HID / 8)            // 524288

__global__ __launch_bounds__(256) void convert3(
    const float* __restrict__ x, const float* __restrict__ wq,
    const float* __restrict__ wo, ushort_t* __restrict__ xb,
    ushort_t* __restrict__ wqb, ushort_t* __restrict__ wob) {
    int i = blockIdx.x * 256 + threadIdx.x;
    const float* s; ushort_t* d; int off;
    if (i < XN8)            { s = x;  d = xb;  off = i; }
    else if (i < XN8 + QN8) { s = wq; d = wqb; off = i - XN8; }
    else                    { s = wo; d = wob; off = i - XN8 - QN8; }
    const float4* sp = (const float4*)s + (size_t)off * 2;
    float4 a = sp[0], b = sp[1];
    *(uint4*)(d + (size_t)off * 8) = make_uint4(
        pk_bf16(a.x, a.y), pk_bf16(a.z, a.w),
        pk_bf16(b.x, b.y), pk_bf16(b.z, b.w));
}

// ---------------------------------------------------------------------------
// gemm_bk64: pure-bf16 GEMM, 64x128 tile, BK=64, XOR-swizzled LDS.
// ROPE: fused in-lane RoPE epilogue for q/k tiles. VT: V tiles stored
// transposed to VtG[vcol][seq] (unchanged from round 14)
// ---------------------------------------------------------------------------
template<bool CF32, bool ROPE, bool VT>
__global__ __launch_bounds__(256) void gemm_bk64(
    const ushort_t* __restrict__ A, const ushort_t* __restrict__ Bt,
    void* __restrict__ Cp, int M, int N, int K,
    const float* __restrict__ cs, const float* __restrict__ sn,
    ushort_t* __restrict__ VtG) {
    __shared__ ushort_t As[64][64];     // 8 KB
    __shared__ ushort_t Bs[128][64];    // 16 KB

    const int t    = threadIdx.x;
    const int wave = t >> 6;
    const int lane = t & 63;
    const int quad = lane >> 4;
    const int l16  = lane & 15;
    const int wm   = (wave >> 1) << 5;
    const int wn   = (wave & 1)  << 6;
    const int bm   = blockIdx.y * 64;
    const int bn   = blockIdx.x * 128;
    const int lr   = lane >> 3;
    const int lc   = ((lane & 7) ^ lr) << 3;

    f32x4 acc[2][4];
    #pragma unroll
    for (int i = 0; i < 2; i++)
        #pragma unroll
        for (int j = 0; j < 4; j++) {
            f32x4 z = {0.f, 0.f, 0.f, 0.f};
            acc[i][j] = z;
        }

    const ushort_t* a0 = &A[(size_t)(bm + wave * 16 + lr) * K + lc];
    const ushort_t* b0 = &Bt[(size_t)(bn + wave * 32 + lr) * K + lc];
    const size_t r8 = (size_t)8 * K;

    for (int k0 = 0; k0 < K; k0 += 64) {
        __syncthreads();
        __builtin_amdgcn_global_load_lds(GLB(a0 + k0),          LDSP(&As[wave * 16][0]),      16, 0, 0);
        __builtin_amdgcn_global_load_lds(GLB(a0 + k0 + r8),     LDSP(&As[wave * 16 + 8][0]),  16, 0, 0);
        __builtin_amdgcn_global_load_lds(GLB(b0 + k0),          LDSP(&Bs[wave * 32][0]),      16, 0, 0);
        __builtin_amdgcn_global_load_lds(GLB(b0 + k0 + r8),     LDSP(&Bs[wave * 32 + 8][0]),  16, 0, 0);
        __builtin_amdgcn_global_load_lds(GLB(b0 + k0 + 2 * r8), LDSP(&Bs[wave * 32 + 16][0]), 16, 0, 0);
        __builtin_amdgcn_global_load_lds(GLB(b0 + k0 + 3 * r8), LDSP(&Bs[wave * 32 + 24][0]), 16, 0, 0);
        __syncthreads();

        #pragma unroll
        for (int ks = 0; ks < 2; ks++) {
            const int ca = (((ks << 2) + quad) ^ (l16 & 7)) << 3;
            bf16x8 af[2], bfr[4];
            #pragma unroll
            for (int i = 0; i < 2; i++)
                af[i] = *(const bf16x8*)&As[wm + i * 16 + l16][ca];
            #pragma unroll
            for (int j = 0; j < 4; j++)
                bfr[j] = *(const bf16x8*)&Bs[wn + j * 16 + l16][ca];

            #pragma unroll
            for (int i = 0; i < 2; i++)
                #pragma unroll
                for (int j = 0; j < 4; j++)
                    acc[i][j] = __builtin_amdgcn_mfma_f32_16x16x32_bf16(
                        af[i], bfr[j], acc[i][j], 0, 0, 0);
        }
    }

    if (ROPE && bn < V_COL) {
        #pragma unroll
        for (int i = 0; i < 2; i++)
            #pragma unroll
            for (int r = 0; r < 4; r++) {
                const int srow = bm + wm + i * 16 + quad * 4 + r;
                float cv[4], sv[4], o[4];
                #pragma unroll
                for (int nd = 0; nd < 4; nd++) {
                    const int d = nd * 16 + l16;
                    cv[nd] = cs[srow * HD + d];
                    sv[nd] = sn[srow * HD + d];
                }
                o[0] = acc[i][0][r] * cv[0] - acc[i][2][r] * sv[0];
                o[1] = acc[i][1][r] * cv[1] - acc[i][3][r] * sv[1];
                o[2] = acc[i][2][r] * cv[2] + acc[i][0][r] * sv[2];
                o[3] = acc[i][3][r] * cv[3] + acc[i][1][r] * sv[3];
                #pragma unroll
                for (int nd = 0; nd < 4; nd++) {
                    const int col = bn + wn + nd * 16 + l16;
                    ((ushort_t*)Cp)[(size_t)srow * N + col] = f2bf(o[nd]);
                }
            }
    } else if (VT && bn >= V_COL) {
        #pragma unroll
        for (int i = 0; i < 2; i++) {
            const int srow0 = bm + wm + i * 16 + quad * 4;
            #pragma unroll
            for (int nd = 0; nd < 4; nd++) {
                const int vcol = bn + wn + nd * 16 + l16 - V_COL;
                uint2 w2 = make_uint2(
                    pk_bf16(acc[i][nd][0], acc[i][nd][1]),
                    pk_bf16(acc[i][nd][2], acc[i][nd][3]));
                *(uint2*)&VtG[(size_t)vcol * S_LEN + srow0] = w2;
            }
        }
    } else {
        #pragma unroll
        for (int i = 0; i < 2; i++)
            #pragma unroll
            for (int j = 0; j < 4; j++)
                #pragma unroll
                for (int r = 0; r < 4; r++) {
                    int row = bm + wm + i * 16 + quad * 4 + r;
                    int col = bn + wn + j * 16 + l16;
                    if (CF32)
                        ((float*)Cp)[(size_t)row * N + col] = acc[i][j][r];
                    else
                        ((ushort_t*)Cp)[(size_t)row * N + col] = f2bf(acc[i][j][r]);
                }
    }
}

// ---------------------------------------------------------------------------
// Fallback GEMM with fused fp32->bf16 staging (small-ws path; unchanged)
// ---------------------------------------------------------------------------
template<bool AF32, bool BF32, bool CF32>
__global__ __launch_bounds__(256) void gemm_bt(
    const void* __restrict__ Ap, const void* __restrict__ Bp,
    void* __restrict__ Cp, int M, int N, int K) {
    __shared__ ushort_t As[128][40];
    __shared__ ushort_t Bs[128][40];

    const int t    = threadIdx.x;
    const int wave = t >> 6;
    const int lane = t & 63;
    const int quad = lane >> 4;
    const int l16  = lane & 15;
    const int wm   = (wave >> 1) << 6;
    const int wn   = (wave & 1)  << 6;
    const int bm   = blockIdx.y * 128;
    const int bn   = blockIdx.x * 128;
    const int sr   = t >> 2;
    const int sc   = (t & 3) << 3;

    f32x4 acc[4][4];
    #pragma unroll
    for (int i = 0; i < 4; i++)
        #pragma unroll
        for (int j = 0; j < 4; j++) {
            f32x4 z = {0.f, 0.f, 0.f, 0.f};
            acc[i][j] = z;
        }

    for (int k0 = 0; k0 < K; k0 += 32) {
        __syncthreads();
        if (AF32) {
            const float* A = (const float*)Ap;
            const float* p0 = &A[(size_t)(bm + sr) * K + k0 + sc];
            const float* p1 = &A[(size_t)(bm + sr + 64) * K + k0 + sc];
            float4 a0 = *(const float4*)p0, a1 = *(const float4*)(p0 + 4);
            float4 b0 = *(const float4*)p1, b1 = *(const float4*)(p1 + 4);
            *(uint4*)&As[sr][sc] = make_uint4(
                pk_bf16(a0.x, a0.y), pk_bf16(a0.z, a0.w),
                pk_bf16(a1.x, a1.y), pk_bf16(a1.z, a1.w));
            *(uint4*)&As[sr + 64][sc] = make_uint4(
                pk_bf16(b0.x, b0.y), pk_bf16(b0.z, b0.w),
                pk_bf16(b1.x, b1.y), pk_bf16(b1.z, b1.w));
        } else {
            const ushort_t* A = (const ushort_t*)Ap;
            *(uint4*)&As[sr][sc]      = *(const uint4*)&A[(size_t)(bm + sr) * K + k0 + sc];
            *(uint4*)&As[sr + 64][sc] = *(const uint4*)&A[(size_t)(bm + sr + 64) * K + k0 + sc];
        }
        if (BF32) {
            const float* B = (const float*)Bp;
            const float* p0 = &B[(size_t)(bn + sr) * K + k0 + sc];
            const float* p1 = &B[(size_t)(bn + sr + 64) * K + k0 + sc];
            float4 a0 = *(const float4*)p0, a1 = *(const float4*)(p0 + 4);
            float4 b0 = *(const float4*)p1, b1 = *(const float4*)(p1 + 4);
            *(uint4*)&Bs[sr][sc] = make_uint4(
                pk_bf16(a0.x, a0.y), pk_bf16(a0.z, a0.w),
                pk_bf16(a1.x, a1.y), pk_bf16(a1.z, a1.w));
            *(uint4*)&Bs[sr + 64][sc] = make_uint4(
                pk_bf16(b0.x, b0.y), pk_bf16(b0.z, b0.w),
                pk_bf16(b1.x, b1.y), pk_bf16(b1.z, b1.w));
        } else {
            const ushort_t* B = (const ushort_t*)Bp;
            *(uint4*)&Bs[sr][sc]      = *(const uint4*)&B[(size_t)(bn + sr) * K + k0 + sc];
            *(uint4*)&Bs[sr + 64][sc] = *(const uint4*)&B[(size_t)(bn + sr + 64) * K + k0 + sc];
        }
        __syncthreads();

        bf16x8 af[4], bfr[4];
        #pragma unroll
        for (int i = 0; i < 4; i++)
            af[i] = *(const bf16x8*)&As[wm + i * 16 + l16][quad * 8];
        #pragma unroll
        for (int j = 0; j < 4; j++)
            bfr[j] = *(const bf16x8*)&Bs[wn + j * 16 + l16][quad * 8];

        #pragma unroll
        for (int i = 0; i < 4; i++)
            #pragma unroll
            for (int j = 0; j < 4; j++)
                acc[i][j] = __builtin_amdgcn_mfma_f32_16x16x32_bf16(
                    af[i], bfr[j], acc[i][j], 0, 0, 0);
    }

    #pragma unroll
    for (int i = 0; i < 4; i++)
        #pragma unroll
        for (int j = 0; j < 4; j++)
            #pragma unroll
            for (int r = 0; r < 4; r++) {
                int row = bm + wm + i * 16 + quad * 4 + r;
                int col = bn + wn + j * 16 + l16;
                if (CF32)
                    ((float*)Cp)[(size_t)row * N + col] = acc[i][j][r];
                else
                    ((ushort_t*)Cp)[(size_t)row * N + col] = f2bf(acc[i][j][r]);
            }
}

// ---------------------------------------------------------------------------
// RoPE standalone (fallback path only)
// ---------------------------------------------------------------------------
__global__ __launch_bounds__(256) void rope_kernel(
    ushort_t* __restrict__ qkv, const float* __restrict__ cs,
    const float* __restrict__ sn) {
    int idx = blockIdx.x * 256 + threadIdx.x;
    if (idx >= S_LEN * (NQH + NKVH)) return;
    int s  = idx / (NQH + NKVH);
    int hh = idx - s * (NQH + NKVH);

    ushort_t* p = &qkv[(size_t)s * QKV_O + hh * HD];
    const uint4* p4 = (const uint4*)p;
    float v[HD], c[HD], sv[HD];
    #pragma unroll
    for (int b = 0; b < 8; b++) unpack8(&v[b * 8], p4[b]);
    const float4* c4 = (const float4*)&cs[s * HD];
    const float4* s4 = (const float4*)&sn[s * HD];
    #pragma unroll
    for (int b = 0; b < 16; b++) {
        ((float4*)c)[b]  = c4[b];
        ((float4*)sv)[b] = s4[b];
    }
    float o[HD];
    #pragma unroll
    for (int d = 0; d < 32; d++) {
        o[d]      = v[d] * c[d]           - v[d + 32] * sv[d];
        o[d + 32] = v[d + 32] * c[d + 32] + v[d]      * sv[d + 32];
    }
    unsigned int* pw = (unsigned int*)p;
    #pragma unroll
    for (int d = 0; d < HD; d += 2)
        pw[d >> 1] = pk_bf16(o[d], o[d + 1]);
}

// ---------------------------------------------------------------------------
// attn_v5: round-12/13 kernel (fallback path; reads V from qkv)
// ---------------------------------------------------------------------------
__global__ __launch_bounds__(256) void attn_v5(
    const ushort_t* __restrict__ qkv, ushort_t* __restrict__ O) {
    const int bx   = blockIdx.x;
    const int h    = bx & 31;
    const int p    = bx >> 5;
    const int kvh  = h >> 2;
    const int q0d  = (31 - p) * 64;
    const int q0s  = p * 64;
    const int tid  = threadIdx.x;
    const int wave = tid >> 6;
    const int lane = tid & 63;
    const int quad = lane >> 4;
    const int l16  = lane & 15;

    __shared__ __align__(16) ushort_t Ks[2][64][72];
    __shared__ __align__(16) ushort_t Vt[2][64][72];
    __shared__ __align__(16) ushort_t Pl[4][32][72];

    const int rowbase0 = q0d + wave * 16;
    const int rowbase1 = q0s + wave * 16;

    bf16x8 bq[2][2];
    #pragma unroll
    for (int mi = 0; mi < 2; mi++) {
        const int rb = (mi == 0) ? rowbase0 : rowbase1;
        #pragma unroll
        for (int ks = 0; ks < 2; ks++) {
            uint4 u = *(const uint4*)&qkv[(size_t)(rb + l16) * QKV_O
                                          + h * HD + ks * 32 + quad * 8];
            float f[8]; unpack8(f, u);
            uint4 w = make_uint4(
                pk_bf16(f[0] * 0.125f, f[1] * 0.125f),
                pk_bf16(f[2] * 0.125f, f[3] * 0.125f),
                pk_bf16(f[4] * 0.125f, f[5] * 0.125f),
                pk_bf16(f[6] * 0.125f, f[7] * 0.125f));
            __builtin_memcpy(&bq[mi][ks], &w, 16);
        }
    }

    bf16x8 ones;
    #pragma unroll
    for (int e = 0; e < 8; e++) ones[e] = (__bf16)1.0f;

    f32x4 acc_o[2][4];
    f32x4 acc_l[2];
    #pragma unroll
    for (int mi = 0; mi < 2; mi++) {
        f32x4 z = {0.f, 0.f, 0.f, 0.f};
        acc_l[mi] = z;
        #pragma unroll
        for (int n = 0; n < 4; n++) acc_o[mi][n] = z;
    }

    const int nt = 32 - p;
    const int sr = tid >> 2;
    const int sc = (tid & 3) << 4;

    {
        const ushort_t* kp = &qkv[(size_t)sr * QKV_O + K_COL + kvh * HD + sc];
        *(uint4*)&Ks[0][sr][sc]     = *(const uint4*)kp;
        *(uint4*)&Ks[0][sr][sc + 8] = *(const uint4*)(kp + 8);
        const ushort_t* vp = &qkv[(size_t)sr * QKV_O + V_COL + kvh * HD + sc];
        ushort_t tmp[16];
        *(uint4*)&tmp[0] = *(const uint4*)vp;
        *(uint4*)&tmp[8] = *(const uint4*)(vp + 8);
        #pragma unroll
        for (int e = 0; e < 16; e++) {
            int d = sc + e;
            Vt[0][d][(sr + 8 * (d >> 3)) & 63] = tmp[e];
        }
    }
    __syncthreads();

    for (int t = 0; t < nt; t++) {
        const int cur = t & 1, nxt = cur ^ 1;
        const int j0 = t * 64;
        const bool hasNext = (t + 1 < nt);

        uint4 ka, kb, va, vb;
        if (hasNext) {
            const size_t rbase = (size_t)(j0 + 64 + sr) * QKV_O;
            const ushort_t* kp = &qkv[rbase + K_COL + kvh * HD + sc];
            ka = *(const uint4*)kp; kb = *(const uint4*)(kp + 8);
            const ushort_t* vp = &qkv[rbase + V_COL + kvh * HD + sc];
            va = *(const uint4*)vp; vb = *(const uint4*)(vp + 8);
        }

        const bool sact = (t <= p);

        f32x4 st[2][4];
        #pragma unroll
        for (int mi = 0; mi < 2; mi++)
            #pragma unroll
            for (int nk = 0; nk < 4; nk++) {
                f32x4 z = {0.f, 0.f, 0.f, 0.f};
                st[mi][nk] = z;
            }
        #pragma unroll
        for (int ks = 0; ks < 2; ks++) {
            bf16x8 ak[4];
            #pragma unroll
            for (int nk = 0; nk < 4; nk++)
                ak[nk] = *(const bf16x8*)&Ks[cur][nk * 16 + l16][ks * 32 + quad * 8];
            #pragma unroll
            for (int mi = 0; mi < 2; mi++) {
                if (mi == 1 && !sact) continue;
                #pragma unroll
                for (int nk = 0; nk < 4; nk++)
                    st[mi][nk] = __builtin_amdgcn_mfma_f32_16x16x32_bf16(
                        ak[nk], bq[mi][ks], st[mi][nk], 0, 0, 0);
            }
        }

        #pragma unroll
        for (int mi = 0; mi < 2; mi++) {
            if (mi == 1 && !sact) continue;
            const bool diag = (mi == 0) ? (t == nt - 1) : (t == p);
            const int qrow = ((mi == 0) ? rowbase0 : rowbase1) + l16;
            #pragma unroll
            for (int nk = 0; nk < 4; nk++) {
                const int kc0 = j0 + nk * 16 + quad * 4;
                float pv[4];
                #pragma unroll
                for (int r = 0; r < 4; r++) {
                    float e = __expf(st[mi][nk][r]);
                    pv[r] = (diag && (kc0 + r > qrow)) ? 0.f : e;
                }
                uint2 w2 = make_uint2(pk_bf16(pv[0], pv[1]), pk_bf16(pv[2], pv[3]));
                *(uint2*)&Pl[wave][mi * 16 + l16][nk * 16 + quad * 4] = w2;
            }
        }

        #pragma unroll
        for (int ksp = 0; ksp < 2; ksp++) {
            bf16x8 bv[4];
            #pragma unroll
            for (int nd = 0; nd < 4; nd++) {
                const int d = nd * 16 + l16;
                bv[nd] = *(const bf16x8*)&Vt[cur][d][(ksp * 32 + quad * 8 + 8 * (d >> 3)) & 63];
            }
            #pragma unroll
            for (int mi = 0; mi < 2; mi++) {
                if (mi == 1 && !sact) continue;
                bf16x8 ap = *(const bf16x8*)&Pl[wave][mi * 16 + l16][ksp * 32 + quad * 8];
                acc_l[mi] = __builtin_amdgcn_mfma_f32_16x16x32_bf16(
                    ap, ones, acc_l[mi], 0, 0, 0);
                #pragma unroll
                for (int nd = 0; nd < 4; nd++)
                    acc_o[mi][nd] = __builtin_amdgcn_mfma_f32_16x16x32_bf16(
                        ap, bv[nd], acc_o[mi][nd], 0, 0, 0);
            }
        }

        if (hasNext) {
            *(uint4*)&Ks[nxt][sr][sc]     = ka;
            *(uint4*)&Ks[nxt][sr][sc + 8] = kb;
            ushort_t tmp[16];
            *(uint4*)&tmp[0] = va;
            *(uint4*)&tmp[8] = vb;
            #pragma unroll
            for (int e = 0; e < 16; e++) {
                int d = sc + e;
                Vt[nxt][d][(sr + 8 * (d >> 3)) & 63] = tmp[e];
            }
        }
        __syncthreads();
    }

    #pragma unroll
    for (int mi = 0; mi < 2; mi++) {
        const int rb = (mi == 0) ? rowbase0 : rowbase1;
        float inv[4];
        #pragma unroll
        for (int r = 0; r < 4; r++) inv[r] = 1.0f / acc_l[mi][r];
        #pragma unroll
        for (int nd = 0; nd < 4; nd++)
            #pragma unroll
            for (int r = 0; r < 4; r++) {
                int row = rb + quad * 4 + r;
                int col = h * HD + nd * 16 + l16;
                O[(size_t)row * (NQH * HD) + col] = f2bf(acc_o[mi][nd][r] * inv[r]);
            }
    }
}

// ---------------------------------------------------------------------------
// attn_v7: 32-row complementary pairing, single m-tile per wave.
// Round-14 counters (MfmaUtil 16 + VALU 44 = 60% combined, occupancy 17% =
// grid-capped 2 blocks/CU) say dependency-stall-bound with nothing to hide
// behind. Here: block (p=0..31, h) = deep 32-row Q-tile D=63-p (waves 0-1)
// + shallow tile S=p (waves 2-3); each wave owns ONE 16-row m-tile (half the
// per-wave chain of v6). Work uniform: nt_d+nt_s = 33 units/block; shallow's
// K-window is contained in deep's so all staged tiles are consumed. Grid
// 1024, LDS 41.2 KB -> 3 blocks/CU = 12 waves/CU (was 8). Activity checks
// are wave-uniform scalar branches. DMA staging + XOR swizzle + dbuf +
// single barrier per tile carried over from v6 unchanged.
// ---------------------------------------------------------------------------
__global__ __launch_bounds__(256) void attn_v7(
    const ushort_t* __restrict__ qkv, const ushort_t* __restrict__ VtG,
    ushort_t* __restrict__ O) {
    const int bx   = blockIdx.x;            // 1024 blocks
    const int h    = bx & 31;
    const int p    = bx >> 5;               // 0..31, p=0 heaviest, first
    const int kvh  = h >> 2;
    const int tid  = threadIdx.x;
    const int wave = tid >> 6;
    const int lane = tid & 63;
    const int quad = lane >> 4;
    const int l16  = lane & 15;

    __shared__ __align__(16) ushort_t Ks[2][64][64];   // 16 KB (DMA, swizzled)
    __shared__ __align__(16) ushort_t Vt[2][64][64];   // 16 KB (DMA, swizzled)
    __shared__ __align__(16) ushort_t Pl[4][16][72];   // 9.2 KB

    const bool deep = (wave < 2);
    const int  widx = wave & 1;
    const int  rowbase = deep ? ((63 - p) * 32 + widx * 16)
                             : (p * 32 + widx * 16);
    const int  nt_d = ((63 - p) >> 1) + 1;   // K-tiles for deep 32-row tile
    const int  nt_s = (p >> 1) + 1;          // K-tiles for shallow tile
    const int  my_nt = deep ? nt_d : nt_s;   // wave-uniform

    // Q B-frag (lane l16 = qrow of this wave's 16 rows), pre-scaled by 1/8
    bf16x8 bq[2];
    #pragma unroll
    for (int ks = 0; ks < 2; ks++) {
        uint4 u = *(const uint4*)&qkv[(size_t)(rowbase + l16) * QKV_O
                                      + h * HD + ks * 32 + quad * 8];
        float f[8]; unpack8(f, u);
        uint4 w = make_uint4(
            pk_bf16(f[0] * 0.125f, f[1] * 0.125f),
            pk_bf16(f[2] * 0.125f, f[3] * 0.125f),
            pk_bf16(f[4] * 0.125f, f[5] * 0.125f),
            pk_bf16(f[6] * 0.125f, f[7] * 0.125f));
        __builtin_memcpy(&bq[ks], &w, 16);
    }

    bf16x8 ones;
    #pragma unroll
    for (int e = 0; e < 8; e++) ones[e] = (__bf16)1.0f;

    f32x4 acc_o[4];
    f32x4 acc_l;
    {
        f32x4 z = {0.f, 0.f, 0.f, 0.f};
        acc_l = z;
        #pragma unroll
        for (int n = 0; n < 4; n++) acc_o[n] = z;
    }

    // DMA lane geometry (XOR swizzle on the source side)
    const int lr = lane >> 3;                 // row-in-group 0..7
    const int cg = ((lane & 7) ^ lr) << 3;    // swizzled global chunk (elems)
    const ushort_t* kbase = &qkv[(size_t)(wave * 16 + lr) * QKV_O + K_COL + kvh * HD + cg];
    const size_t    kr8   = (size_t)8 * QKV_O;
    const ushort_t* vbase = &VtG[(size_t)(kvh * HD + wave * 16 + lr) * S_LEN + cg];
    const size_t    vr8   = (size_t)8 * S_LEN;

    const int nt = nt_d;                      // loop bound (shallow ⊆ deep window)

    // ---- prologue: DMA tile 0 -> buffer 0 ----
    __builtin_amdgcn_global_load_lds(GLB(kbase),       LDSP(&Ks[0][wave * 16][0]),     16, 0, 0);
    __builtin_amdgcn_global_load_lds(GLB(kbase + kr8), LDSP(&Ks[0][wave * 16 + 8][0]), 16, 0, 0);
    __builtin_amdgcn_global_load_lds(GLB(vbase),       LDSP(&Vt[0][wave * 16][0]),     16, 0, 0);
    __builtin_amdgcn_global_load_lds(GLB(vbase + vr8), LDSP(&Vt[0][wave * 16 + 8][0]), 16, 0, 0);
    __syncthreads();

    for (int t = 0; t < nt; t++) {
        const int cur = t & 1, nxt = cur ^ 1;
        const int j0 = t * 64;

        // ---- DMA-prefetch tile t+1 -> alternate buffer ----
        if (t + 1 < nt) {
            const size_t kj = (size_t)(j0 + 64) * QKV_O;
            __builtin_amdgcn_global_load_lds(GLB(kbase + kj),           LDSP(&Ks[nxt][wave * 16][0]),     16, 0, 0);
            __builtin_amdgcn_global_load_lds(GLB(kbase + kj + kr8),     LDSP(&Ks[nxt][wave * 16 + 8][0]), 16, 0, 0);
            __builtin_amdgcn_global_load_lds(GLB(vbase + j0 + 64),      LDSP(&Vt[nxt][wave * 16][0]),     16, 0, 0);
            __builtin_amdgcn_global_load_lds(GLB(vbase + j0 + 64 + vr8),LDSP(&Vt[nxt][wave * 16 + 8][0]), 16, 0, 0);
        }

        const bool active = (t < my_nt);      // wave-uniform scalar branch
        if (active) {
            // ---- S^T = K·Q^T ----
            f32x4 st[4];
            #pragma unroll
            for (int nk = 0; nk < 4; nk++) {
                f32x4 z = {0.f, 0.f, 0.f, 0.f};
                st[nk] = z;
            }
            #pragma unroll
            for (int ks = 0; ks < 2; ks++) {
                const int ca = (((ks << 2) + quad) ^ (l16 & 7)) << 3;
                #pragma unroll
                for (int nk = 0; nk < 4; nk++) {
                    bf16x8 ak = *(const bf16x8*)&Ks[cur][nk * 16 + l16][ca];
                    st[nk] = __builtin_amdgcn_mfma_f32_16x16x32_bf16(
                        ak, bq[ks], st[nk], 0, 0, 0);
                }
            }

            // ---- exp + causal mask, b64 P stores ----
            const bool diag = (t == my_nt - 1);
            const int qrow = rowbase + l16;
            #pragma unroll
            for (int nk = 0; nk < 4; nk++) {
                const int kc0 = j0 + nk * 16 + quad * 4;
                float pv[4];
                #pragma unroll
                for (int r = 0; r < 4; r++) {
                    float e = __expf(st[nk][r]);
                    pv[r] = (diag && (kc0 + r > qrow)) ? 0.f : e;
                }
                uint2 w2 = make_uint2(pk_bf16(pv[0], pv[1]), pk_bf16(pv[2], pv[3]));
                *(uint2*)&Pl[wave][l16][nk * 16 + quad * 4] = w2;
            }

            // ---- l += P·1 ; O += P·V ----
            #pragma unroll
            for (int ksp = 0; ksp < 2; ksp++) {
                const int ca = (((ksp << 2) + quad) ^ (l16 & 7)) << 3;
                bf16x8 ap = *(const bf16x8*)&Pl[wave][l16][ksp * 32 + quad * 8];
                acc_l = __builtin_amdgcn_mfma_f32_16x16x32_bf16(
                    ap, ones, acc_l, 0, 0, 0);
                #pragma unroll
                for (int nd = 0; nd < 4; nd++) {
                    bf16x8 bv = *(const bf16x8*)&Vt[cur][nd * 16 + l16][ca];
                    acc_o[nd] = __builtin_amdgcn_mfma_f32_16x16x32_bf16(
                        ap, bv, acc_o[nd], 0, 0, 0);
                }
            }
        }
        __syncthreads();   // one barrier/tile; drains DMA + retires cur
    }

    // ---- epilogue: O / l ----
    float inv[4];
    #pragma unroll
    for (int r = 0; r < 4; r++) inv[r] = 1.0f / acc_l[r];
    #pragma unroll
    for (int nd = 0; nd < 4; nd++)
        #pragma unroll
        for (int r = 0; r < 4; r++) {
            int row = rowbase + quad * 4 + r;
            int col = h * HD + nd * 16 + l16;
            O[(size_t)row * (NQH * HD) + col] = f2bf(acc_o[nd][r] * inv[r]);
        }
}

// ---------------------------------------------------------------------------
extern "C" void kernel_launch(void* const* d_in, const int* in_sizes, int n_in,
                              void* d_out, int out_size, void* d_ws, size_t ws_size,
                              hipStream_t stream) {
    const float* x     = (const float*)d_in[0];  // [2048][2048] fp32
    const float* cosp  = (const float*)d_in[1];  // [2048][64]   fp32
    const float* sinp  = (const float*)d_in[2];  // [2048][64]   fp32
    const float* w_qkv = (const float*)d_in[3];  // [3072][2048] fp32
    const float* w_out = (const float*)d_in[4];  // [2048][2048] fp32
    float* out = (float*)d_out;                  // [2048][2048] fp32

    const size_t NQKV = (size_t)S_LEN * QKV_O;   // 6291456
    const size_t NH2  = (size_t)S_LEN * HID;     // 4194304
    const size_t NVT  = (size_t)(NKVH * HD) * S_LEN;  // 1048576
    const size_t need_old = 2 * (NQKV + NH2) * sizeof(ushort_t);        // 41.9 MB
    const size_t need_new = need_old + NVT * sizeof(ushort_t);          // 44.0 MB

    ushort_t* qkv = (ushort_t*)d_ws;             // bf16 [2048][3072]
    ushort_t* x_bf    = qkv + NQKV;
    ushort_t* attnO   = x_bf;                    // disjoint lifetimes
    ushort_t* wqkv_bf = x_bf + NH2;
    ushort_t* wout_bf = wqkv_bf + NQKV;
    ushort_t* VtG     = wout_bf + NH2;           // bf16 [512][2048]

    if (ws_size >= need_new) {
        convert3<<<XN8 / 256 + QN8 / 256 + ON8 / 256, 256, 0, stream>>>(
            x, w_qkv, w_out, x_bf, wqkv_bf, wout_bf);

        // 1) qkv(q,k w/ RoPE) + VtG(V^T) = x @ w_qkv^T
        dim3 g1(QKV_O / 128, S_LEN / 64);
        gemm_bk64<false, true, true><<<g1, 256, 0, stream>>>(
            x_bf, wqkv_bf, qkv, S_LEN, QKV_O, HID, cosp, sinp, VtG);

        // 2) causal GQA attention (32-row pairing, 1024 blocks, 3/CU)
        attn_v7<<<32 * NQH, 256, 0, stream>>>(qkv, VtG, attnO);

        // 3) out = attnO @ w_out^T
        dim3 g2(HID / 128, S_LEN / 64);
        gemm_bk64<true, false, false><<<g2, 256, 0, stream>>>(
            attnO, wout_bf, out, S_LEN, HID, HID, nullptr, nullptr, nullptr);
    } else if (ws_size >= need_old) {
        convert3<<<XN8 / 256 + QN8 / 256 + ON8 / 256, 256, 0, stream>>>(
            x, w_qkv, w_out, x_bf, wqkv_bf, wout_bf);

        dim3 g1(QKV_O / 128, S_LEN / 64);
        gemm_bk64<false, true, false><<<g1, 256, 0, stream>>>(
            x_bf, wqkv_bf, qkv, S_LEN, QKV_O, HID, cosp, sinp, nullptr);

        attn_v5<<<16 * NQH, 256, 0, stream>>>(qkv, attnO);

        dim3 g2(HID / 128, S_LEN / 64);
        gemm_bk64<true, false, false><<<g2, 256, 0, stream>>>(
            attnO, wout_bf, out, S_LEN, HID, HID, nullptr, nullptr, nullptr);
    } else {
        ushort_t* attnO2 = qkv + NQKV;

        dim3 g1(QKV_O / 128, S_LEN / 128);
        gemm_bt<true, true, false><<<g1, 256, 0, stream>>>(x, w_qkv, qkv, S_LEN, QKV_O, HID);

        int rope_threads = S_LEN * (NQH + NKVH);
        rope_kernel<<<(rope_threads + 255) / 256, 256, 0, stream>>>(qkv, cosp, sinp);

        attn_v5<<<16 * NQH, 256, 0, stream>>>(qkv, attnO2);

        dim3 g2(HID / 128, S_LEN / 128);
        gemm_bt<false, true, true><<<g2, 256, 0, stream>>>(attnO2, w_out, out, S_LEN, HID, HID);
    }
}

// Round 16
// 211.184 us; speedup vs baseline: 1.0500x; 1.0500x over previous
//
#include <hip/hip_runtime.h>
#include <hip/hip_bf16.h>
#include <stdint.h>

// Problem constants (B=1). I/O dtype: fp32. Internals bf16 (MFMA path).
#define S_LEN 2048
#define HID   2048
#define NQH   32
#define NKVH  8
#define HD    64
#define QKV_O 3072      // (32 + 2*8) * 64
#define K_COL 2048      // col offset of K block in qkv row
#define V_COL 2560      // col offset of V block in qkv row

typedef unsigned short ushort_t;
typedef __bf16 bf16x8 __attribute__((ext_vector_type(8)));
typedef float  f32x4  __attribute__((ext_vector_type(4)));

#define GLB(p) ((const __attribute__((address_space(1))) void*)(p))
#define LDSP(p) ((__attribute__((address_space(3))) void*)(p))

// Q pre-scale: 1/sqrt(64) * log2(e), folded so softmax uses exp2 (saves one
// v_mul per exp). Applied in fp32 BEFORE bf16 rounding -> no extra systematic
// quantization vs the 0.125-exact scale.
#define QSCALE 0.18033688011112042f

__device__ __forceinline__ ushort_t f2bf(float f) {
    unsigned int x = __float_as_uint(f);
    unsigned int r = (x + 0x7fffu + ((x >> 16) & 1u)) >> 16;   // RNE
    return (ushort_t)r;
}
__device__ __forceinline__ unsigned int pk_bf16(float a, float b) {
    __hip_bfloat162 h = __float22bfloat162_rn(make_float2(a, b));
    unsigned int r;
    __builtin_memcpy(&r, &h, 4);
    return r;
}
__device__ __forceinline__ void unpack8(float* dst, uint4 u) {
    dst[0] = __uint_as_float(u.x << 16); dst[1] = __uint_as_float(u.x & 0xffff0000u);
    dst[2] = __uint_as_float(u.y << 16); dst[3] = __uint_as_float(u.y & 0xffff0000u);
    dst[4] = __uint_as_float(u.z << 16); dst[5] = __uint_as_float(u.z & 0xffff0000u);
    dst[6] = __uint_as_float(u.w << 16); dst[7] = __uint_as_float(u.w & 0xffff0000u);
}

// ---------------------------------------------------------------------------
// convert3: fp32 -> bf16 for x, w_qkv, w_out
// ---------------------------------------------------------------------------
#define XN8 (S_LEN * HID / 8)          // 524288
#define QN8 (QKV_O * HID / 8)          // 786432
#define ON8 (HID * HID / 8)            // 524288

__global__ __launch_bounds__(256) void convert3(
    const float* __restrict__ x, const float* __restrict__ wq,
    const float* __restrict__ wo, ushort_t* __restrict__ xb,
    ushort_t* __restrict__ wqb, ushort_t* __restrict__ wob) {
    int i = blockIdx.x * 256 + threadIdx.x;
    const float* s; ushort_t* d; int off;
    if (i < XN8)            { s = x;  d = xb;  off = i; }
    else if (i < XN8 + QN8) { s = wq; d = wqb; off = i - XN8; }
    else                    { s = wo; d = wob; off = i - XN8 - QN8; }
    const float4* sp = (const float4*)s + (size_t)off * 2;
    float4 a = sp[0], b = sp[1];
    *(uint4*)(d + (size_t)off * 8) = make_uint4(
        pk_bf16(a.x, a.y), pk_bf16(a.z, a.w),
        pk_bf16(b.x, b.y), pk_bf16(b.z, b.w));
}

// ---------------------------------------------------------------------------
// gemm_bk64: pure-bf16 GEMM, 64x128 tile, BK=64, XOR-swizzled LDS.
// ROPE: fused in-lane RoPE epilogue for q/k tiles (bn < V_COL).
// VT:   V tiles (bn >= V_COL) stored transposed to VtG[vcol][seq].
// (round-14 proven structure, unchanged)
// ---------------------------------------------------------------------------
template<bool CF32, bool ROPE, bool VT>
__global__ __launch_bounds__(256) void gemm_bk64(
    const ushort_t* __restrict__ A, const ushort_t* __restrict__ Bt,
    void* __restrict__ Cp, int M, int N, int K,
    const float* __restrict__ cs, const float* __restrict__ sn,
    ushort_t* __restrict__ VtG) {
    __shared__ ushort_t As[64][64];     // 8 KB
    __shared__ ushort_t Bs[128][64];    // 16 KB

    const int t    = threadIdx.x;
    const int wave = t >> 6;
    const int lane = t & 63;
    const int quad = lane >> 4;
    const int l16  = lane & 15;
    const int wm   = (wave >> 1) << 5;
    const int wn   = (wave & 1)  << 6;
    const int bm   = blockIdx.y * 64;
    const int bn   = blockIdx.x * 128;
    const int lr   = lane >> 3;
    const int lc   = ((lane & 7) ^ lr) << 3;

    f32x4 acc[2][4];
    #pragma unroll
    for (int i = 0; i < 2; i++)
        #pragma unroll
        for (int j = 0; j < 4; j++) {
            f32x4 z = {0.f, 0.f, 0.f, 0.f};
            acc[i][j] = z;
        }

    const ushort_t* a0 = &A[(size_t)(bm + wave * 16 + lr) * K + lc];
    const ushort_t* b0 = &Bt[(size_t)(bn + wave * 32 + lr) * K + lc];
    const size_t r8 = (size_t)8 * K;

    for (int k0 = 0; k0 < K; k0 += 64) {
        __syncthreads();
        __builtin_amdgcn_global_load_lds(GLB(a0 + k0),          LDSP(&As[wave * 16][0]),      16, 0, 0);
        __builtin_amdgcn_global_load_lds(GLB(a0 + k0 + r8),     LDSP(&As[wave * 16 + 8][0]),  16, 0, 0);
        __builtin_amdgcn_global_load_lds(GLB(b0 + k0),          LDSP(&Bs[wave * 32][0]),      16, 0, 0);
        __builtin_amdgcn_global_load_lds(GLB(b0 + k0 + r8),     LDSP(&Bs[wave * 32 + 8][0]),  16, 0, 0);
        __builtin_amdgcn_global_load_lds(GLB(b0 + k0 + 2 * r8), LDSP(&Bs[wave * 32 + 16][0]), 16, 0, 0);
        __builtin_amdgcn_global_load_lds(GLB(b0 + k0 + 3 * r8), LDSP(&Bs[wave * 32 + 24][0]), 16, 0, 0);
        __syncthreads();

        #pragma unroll
        for (int ks = 0; ks < 2; ks++) {
            const int ca = (((ks << 2) + quad) ^ (l16 & 7)) << 3;
            bf16x8 af[2], bfr[4];
            #pragma unroll
            for (int i = 0; i < 2; i++)
                af[i] = *(const bf16x8*)&As[wm + i * 16 + l16][ca];
            #pragma unroll
            for (int j = 0; j < 4; j++)
                bfr[j] = *(const bf16x8*)&Bs[wn + j * 16 + l16][ca];

            #pragma unroll
            for (int i = 0; i < 2; i++)
                #pragma unroll
                for (int j = 0; j < 4; j++)
                    acc[i][j] = __builtin_amdgcn_mfma_f32_16x16x32_bf16(
                        af[i], bfr[j], acc[i][j], 0, 0, 0);
        }
    }

    if (ROPE && bn < V_COL) {
        #pragma unroll
        for (int i = 0; i < 2; i++)
            #pragma unroll
            for (int r = 0; r < 4; r++) {
                const int srow = bm + wm + i * 16 + quad * 4 + r;
                float cv[4], sv[4], o[4];
                #pragma unroll
                for (int nd = 0; nd < 4; nd++) {
                    const int d = nd * 16 + l16;
                    cv[nd] = cs[srow * HD + d];
                    sv[nd] = sn[srow * HD + d];
                }
                o[0] = acc[i][0][r] * cv[0] - acc[i][2][r] * sv[0];
                o[1] = acc[i][1][r] * cv[1] - acc[i][3][r] * sv[1];
                o[2] = acc[i][2][r] * cv[2] + acc[i][0][r] * sv[2];
                o[3] = acc[i][3][r] * cv[3] + acc[i][1][r] * sv[3];
                #pragma unroll
                for (int nd = 0; nd < 4; nd++) {
                    const int col = bn + wn + nd * 16 + l16;
                    ((ushort_t*)Cp)[(size_t)srow * N + col] = f2bf(o[nd]);
                }
            }
    } else if (VT && bn >= V_COL) {
        #pragma unroll
        for (int i = 0; i < 2; i++) {
            const int srow0 = bm + wm + i * 16 + quad * 4;
            #pragma unroll
            for (int nd = 0; nd < 4; nd++) {
                const int vcol = bn + wn + nd * 16 + l16 - V_COL;
                uint2 w2 = make_uint2(
                    pk_bf16(acc[i][nd][0], acc[i][nd][1]),
                    pk_bf16(acc[i][nd][2], acc[i][nd][3]));
                *(uint2*)&VtG[(size_t)vcol * S_LEN + srow0] = w2;
            }
        }
    } else {
        #pragma unroll
        for (int i = 0; i < 2; i++)
            #pragma unroll
            for (int j = 0; j < 4; j++)
                #pragma unroll
                for (int r = 0; r < 4; r++) {
                    int row = bm + wm + i * 16 + quad * 4 + r;
                    int col = bn + wn + j * 16 + l16;
                    if (CF32)
                        ((float*)Cp)[(size_t)row * N + col] = acc[i][j][r];
                    else
                        ((ushort_t*)Cp)[(size_t)row * N + col] = f2bf(acc[i][j][r]);
                }
    }
}

// ---------------------------------------------------------------------------
// Fallback GEMM with fused fp32->bf16 staging (small-ws path; unchanged)
// ---------------------------------------------------------------------------
template<bool AF32, bool BF32, bool CF32>
__global__ __launch_bounds__(256) void gemm_bt(
    const void* __restrict__ Ap, const void* __restrict__ Bp,
    void* __restrict__ Cp, int M, int N, int K) {
    __shared__ ushort_t As[128][40];
    __shared__ ushort_t Bs[128][40];

    const int t    = threadIdx.x;
    const int wave = t >> 6;
    const int lane = t & 63;
    const int quad = lane >> 4;
    const int l16  = lane & 15;
    const int wm   = (wave >> 1) << 6;
    const int wn   = (wave & 1)  << 6;
    const int bm   = blockIdx.y * 128;
    const int bn   = blockIdx.x * 128;
    const int sr   = t >> 2;
    const int sc   = (t & 3) << 3;

    f32x4 acc[4][4];
    #pragma unroll
    for (int i = 0; i < 4; i++)
        #pragma unroll
        for (int j = 0; j < 4; j++) {
            f32x4 z = {0.f, 0.f, 0.f, 0.f};
            acc[i][j] = z;
        }

    for (int k0 = 0; k0 < K; k0 += 32) {
        __syncthreads();
        if (AF32) {
            const float* A = (const float*)Ap;
            const float* p0 = &A[(size_t)(bm + sr) * K + k0 + sc];
            const float* p1 = &A[(size_t)(bm + sr + 64) * K + k0 + sc];
            float4 a0 = *(const float4*)p0, a1 = *(const float4*)(p0 + 4);
            float4 b0 = *(const float4*)p1, b1 = *(const float4*)(p1 + 4);
            *(uint4*)&As[sr][sc] = make_uint4(
                pk_bf16(a0.x, a0.y), pk_bf16(a0.z, a0.w),
                pk_bf16(a1.x, a1.y), pk_bf16(a1.z, a1.w));
            *(uint4*)&As[sr + 64][sc] = make_uint4(
                pk_bf16(b0.x, b0.y), pk_bf16(b0.z, b0.w),
                pk_bf16(b1.x, b1.y), pk_bf16(b1.z, b1.w));
        } else {
            const ushort_t* A = (const ushort_t*)Ap;
            *(uint4*)&As[sr][sc]      = *(const uint4*)&A[(size_t)(bm + sr) * K + k0 + sc];
            *(uint4*)&As[sr + 64][sc] = *(const uint4*)&A[(size_t)(bm + sr + 64) * K + k0 + sc];
        }
        if (BF32) {
            const float* B = (const float*)Bp;
            const float* p0 = &B[(size_t)(bn + sr) * K + k0 + sc];
            const float* p1 = &B[(size_t)(bn + sr + 64) * K + k0 + sc];
            float4 a0 = *(const float4*)p0, a1 = *(const float4*)(p0 + 4);
            float4 b0 = *(const float4*)p1, b1 = *(const float4*)(p1 + 4);
            *(uint4*)&Bs[sr][sc] = make_uint4(
                pk_bf16(a0.x, a0.y), pk_bf16(a0.z, a0.w),
                pk_bf16(a1.x, a1.y), pk_bf16(a1.z, a1.w));
            *(uint4*)&Bs[sr + 64][sc] = make_uint4(
                pk_bf16(b0.x, b0.y), pk_bf16(b0.z, b0.w),
                pk_bf16(b1.x, b1.y), pk_bf16(b1.z, b1.w));
        } else {
            const ushort_t* B = (const ushort_t*)Bp;
            *(uint4*)&Bs[sr][sc]      = *(const uint4*)&B[(size_t)(bn + sr) * K + k0 + sc];
            *(uint4*)&Bs[sr + 64][sc] = *(const uint4*)&B[(size_t)(bn + sr + 64) * K + k0 + sc];
        }
        __syncthreads();

        bf16x8 af[4], bfr[4];
        #pragma unroll
        for (int i = 0; i < 4; i++)
            af[i] = *(const bf16x8*)&As[wm + i * 16 + l16][quad * 8];
        #pragma unroll
        for (int j = 0; j < 4; j++)
            bfr[j] = *(const bf16x8*)&Bs[wn + j * 16 + l16][quad * 8];

        #pragma unroll
        for (int i = 0; i < 4; i++)
            #pragma unroll
            for (int j = 0; j < 4; j++)
                acc[i][j] = __builtin_amdgcn_mfma_f32_16x16x32_bf16(
                    af[i], bfr[j], acc[i][j], 0, 0, 0);
    }

    #pragma unroll
    for (int i = 0; i < 4; i++)
        #pragma unroll
        for (int j = 0; j < 4; j++)
            #pragma unroll
            for (int r = 0; r < 4; r++) {
                int row = bm + wm + i * 16 + quad * 4 + r;
                int col = bn + wn + j * 16 + l16;
                if (CF32)
                    ((float*)Cp)[(size_t)row * N + col] = acc[i][j][r];
                else
                    ((ushort_t*)Cp)[(size_t)row * N + col] = f2bf(acc[i][j][r]);
            }
}

// ---------------------------------------------------------------------------
// RoPE standalone (fallback path only)
// ---------------------------------------------------------------------------
__global__ __launch_bounds__(256) void rope_kernel(
    ushort_t* __restrict__ qkv, const float* __restrict__ cs,
    const float* __restrict__ sn) {
    int idx = blockIdx.x * 256 + threadIdx.x;
    if (idx >= S_LEN * (NQH + NKVH)) return;
    int s  = idx / (NQH + NKVH);
    int hh = idx - s * (NQH + NKVH);

    ushort_t* p = &qkv[(size_t)s * QKV_O + hh * HD];
    const uint4* p4 = (const uint4*)p;
    float v[HD], c[HD], sv[HD];
    #pragma unroll
    for (int b = 0; b < 8; b++) unpack8(&v[b * 8], p4[b]);
    const float4* c4 = (const float4*)&cs[s * HD];
    const float4* s4 = (const float4*)&sn[s * HD];
    #pragma unroll
    for (int b = 0; b < 16; b++) {
        ((float4*)c)[b]  = c4[b];
        ((float4*)sv)[b] = s4[b];
    }
    float o[HD];
    #pragma unroll
    for (int d = 0; d < 32; d++) {
        o[d]      = v[d] * c[d]           - v[d + 32] * sv[d];
        o[d + 32] = v[d + 32] * c[d + 32] + v[d]      * sv[d + 32];
    }
    unsigned int* pw = (unsigned int*)p;
    #pragma unroll
    for (int d = 0; d < HD; d += 2)
        pw[d >> 1] = pk_bf16(o[d], o[d + 1]);
}

// ---------------------------------------------------------------------------
// attn_v5: round-12/13 kernel (fallback path; reads V from qkv)
// ---------------------------------------------------------------------------
__global__ __launch_bounds__(256) void attn_v5(
    const ushort_t* __restrict__ qkv, ushort_t* __restrict__ O) {
    const int bx   = blockIdx.x;
    const int h    = bx & 31;
    const int p    = bx >> 5;
    const int kvh  = h >> 2;
    const int q0d  = (31 - p) * 64;
    const int q0s  = p * 64;
    const int tid  = threadIdx.x;
    const int wave = tid >> 6;
    const int lane = tid & 63;
    const int quad = lane >> 4;
    const int l16  = lane & 15;

    __shared__ __align__(16) ushort_t Ks[2][64][72];
    __shared__ __align__(16) ushort_t Vt[2][64][72];
    __shared__ __align__(16) ushort_t Pl[4][32][72];

    const int rowbase0 = q0d + wave * 16;
    const int rowbase1 = q0s + wave * 16;

    bf16x8 bq[2][2];
    #pragma unroll
    for (int mi = 0; mi < 2; mi++) {
        const int rb = (mi == 0) ? rowbase0 : rowbase1;
        #pragma unroll
        for (int ks = 0; ks < 2; ks++) {
            uint4 u = *(const uint4*)&qkv[(size_t)(rb + l16) * QKV_O
                                          + h * HD + ks * 32 + quad * 8];
            float f[8]; unpack8(f, u);
            uint4 w = make_uint4(
                pk_bf16(f[0] * QSCALE, f[1] * QSCALE),
                pk_bf16(f[2] * QSCALE, f[3] * QSCALE),
                pk_bf16(f[4] * QSCALE, f[5] * QSCALE),
                pk_bf16(f[6] * QSCALE, f[7] * QSCALE));
            __builtin_memcpy(&bq[mi][ks], &w, 16);
        }
    }

    bf16x8 ones;
    #pragma unroll
    for (int e = 0; e < 8; e++) ones[e] = (__bf16)1.0f;

    f32x4 acc_o[2][4];
    f32x4 acc_l[2];
    #pragma unroll
    for (int mi = 0; mi < 2; mi++) {
        f32x4 z = {0.f, 0.f, 0.f, 0.f};
        acc_l[mi] = z;
        #pragma unroll
        for (int n = 0; n < 4; n++) acc_o[mi][n] = z;
    }

    const int nt = 32 - p;
    const int sr = tid >> 2;
    const int sc = (tid & 3) << 4;

    {
        const ushort_t* kp = &qkv[(size_t)sr * QKV_O + K_COL + kvh * HD + sc];
        *(uint4*)&Ks[0][sr][sc]     = *(const uint4*)kp;
        *(uint4*)&Ks[0][sr][sc + 8] = *(const uint4*)(kp + 8);
        const ushort_t* vp = &qkv[(size_t)sr * QKV_O + V_COL + kvh * HD + sc];
        ushort_t tmp[16];
        *(uint4*)&tmp[0] = *(const uint4*)vp;
        *(uint4*)&tmp[8] = *(const uint4*)(vp + 8);
        #pragma unroll
        for (int e = 0; e < 16; e++) {
            int d = sc + e;
            Vt[0][d][(sr + 8 * (d >> 3)) & 63] = tmp[e];
        }
    }
    __syncthreads();

    for (int t = 0; t < nt; t++) {
        const int cur = t & 1, nxt = cur ^ 1;
        const int j0 = t * 64;
        const bool hasNext = (t + 1 < nt);

        uint4 ka, kb, va, vb;
        if (hasNext) {
            const size_t rbase = (size_t)(j0 + 64 + sr) * QKV_O;
            const ushort_t* kp = &qkv[rbase + K_COL + kvh * HD + sc];
            ka = *(const uint4*)kp; kb = *(const uint4*)(kp + 8);
            const ushort_t* vp = &qkv[rbase + V_COL + kvh * HD + sc];
            va = *(const uint4*)vp; vb = *(const uint4*)(vp + 8);
        }

        const bool sact = (t <= p);

        f32x4 st[2][4];
        #pragma unroll
        for (int mi = 0; mi < 2; mi++)
            #pragma unroll
            for (int nk = 0; nk < 4; nk++) {
                f32x4 z = {0.f, 0.f, 0.f, 0.f};
                st[mi][nk] = z;
            }
        #pragma unroll
        for (int ks = 0; ks < 2; ks++) {
            bf16x8 ak[4];
            #pragma unroll
            for (int nk = 0; nk < 4; nk++)
                ak[nk] = *(const bf16x8*)&Ks[cur][nk * 16 + l16][ks * 32 + quad * 8];
            #pragma unroll
            for (int mi = 0; mi < 2; mi++) {
                if (mi == 1 && !sact) continue;
                #pragma unroll
                for (int nk = 0; nk < 4; nk++)
                    st[mi][nk] = __builtin_amdgcn_mfma_f32_16x16x32_bf16(
                        ak[nk], bq[mi][ks], st[mi][nk], 0, 0, 0);
            }
        }

        #pragma unroll
        for (int mi = 0; mi < 2; mi++) {
            if (mi == 1 && !sact) continue;
            const bool diag = (mi == 0) ? (t == nt - 1) : (t == p);
            const int qrow = ((mi == 0) ? rowbase0 : rowbase1) + l16;
            #pragma unroll
            for (int nk = 0; nk < 4; nk++) {
                const int kc0 = j0 + nk * 16 + quad * 4;
                float pv[4];
                #pragma unroll
                for (int r = 0; r < 4; r++) {
                    float e = exp2f(st[mi][nk][r]);
                    pv[r] = (diag && (kc0 + r > qrow)) ? 0.f : e;
                }
                uint2 w2 = make_uint2(pk_bf16(pv[0], pv[1]), pk_bf16(pv[2], pv[3]));
                *(uint2*)&Pl[wave][mi * 16 + l16][nk * 16 + quad * 4] = w2;
            }
        }

        #pragma unroll
        for (int ksp = 0; ksp < 2; ksp++) {
            bf16x8 bv[4];
            #pragma unroll
            for (int nd = 0; nd < 4; nd++) {
                const int d = nd * 16 + l16;
                bv[nd] = *(const bf16x8*)&Vt[cur][d][(ksp * 32 + quad * 8 + 8 * (d >> 3)) & 63];
            }
            #pragma unroll
            for (int mi = 0; mi < 2; mi++) {
                if (mi == 1 && !sact) continue;
                bf16x8 ap = *(const bf16x8*)&Pl[wave][mi * 16 + l16][ksp * 32 + quad * 8];
                acc_l[mi] = __builtin_amdgcn_mfma_f32_16x16x32_bf16(
                    ap, ones, acc_l[mi], 0, 0, 0);
                #pragma unroll
                for (int nd = 0; nd < 4; nd++)
                    acc_o[mi][nd] = __builtin_amdgcn_mfma_f32_16x16x32_bf16(
                        ap, bv[nd], acc_o[mi][nd], 0, 0, 0);
            }
        }

        if (hasNext) {
            *(uint4*)&Ks[nxt][sr][sc]     = ka;
            *(uint4*)&Ks[nxt][sr][sc + 8] = kb;
            ushort_t tmp[16];
            *(uint4*)&tmp[0] = va;
            *(uint4*)&tmp[8] = vb;
            #pragma unroll
            for (int e = 0; e < 16; e++) {
                int d = sc + e;
                Vt[nxt][d][(sr + 8 * (d >> 3)) & 63] = tmp[e];
            }
        }
        __syncthreads();
    }

    #pragma unroll
    for (int mi = 0; mi < 2; mi++) {
        const int rb = (mi == 0) ? rowbase0 : rowbase1;
        float inv[4];
        #pragma unroll
        for (int r = 0; r < 4; r++) inv[r] = 1.0f / acc_l[mi][r];
        #pragma unroll
        for (int nd = 0; nd < 4; nd++)
            #pragma unroll
            for (int r = 0; r < 4; r++) {
                int row = rb + quad * 4 + r;
                int col = h * HD + nd * 16 + l16;
                O[(size_t)row * (NQH * HD) + col] = f2bf(acc_o[mi][nd][r] * inv[r]);
            }
    }
}

// ---------------------------------------------------------------------------
// attn_v6: complementary 64-row pairing + S^T orientation + full DMA staging
// (round-14 proven kernel, 45.6 us — restored after v7's regression showed
// pairing-at-64 is the staging-efficiency optimum: 32-row blocks doubled
// total K/V-tile stagings + barriers, MfmaUtil 16->11%). Only change vs
// round 14: Q pre-scale folds log2(e) and softmax uses exp2f.
// ---------------------------------------------------------------------------
__global__ __launch_bounds__(256) void attn_v6(
    const ushort_t* __restrict__ qkv, const ushort_t* __restrict__ VtG,
    ushort_t* __restrict__ O) {
    const int bx   = blockIdx.x;            // 512 blocks
    const int h    = bx & 31;
    const int p    = bx >> 5;               // 0..15, p=0 heaviest, first
    const int kvh  = h >> 2;
    const int q0d  = (31 - p) * 64;
    const int q0s  = p * 64;
    const int tid  = threadIdx.x;
    const int wave = tid >> 6;
    const int lane = tid & 63;
    const int quad = lane >> 4;
    const int l16  = lane & 15;

    __shared__ __align__(16) ushort_t Ks[2][64][64];   // 16 KB (DMA, swizzled)
    __shared__ __align__(16) ushort_t Vt[2][64][64];   // 16 KB (DMA, swizzled)
    __shared__ __align__(16) ushort_t Pl[4][32][72];   // 18 KB

    const int rowbase0 = q0d + wave * 16;
    const int rowbase1 = q0s + wave * 16;

    // Q B-frags (lane l16 = qrow), pre-scaled by 1/8*log2(e) in fp32
    bf16x8 bq[2][2];
    #pragma unroll
    for (int mi = 0; mi < 2; mi++) {
        const int rb = (mi == 0) ? rowbase0 : rowbase1;
        #pragma unroll
        for (int ks = 0; ks < 2; ks++) {
            uint4 u = *(const uint4*)&qkv[(size_t)(rb + l16) * QKV_O
                                          + h * HD + ks * 32 + quad * 8];
            float f[8]; unpack8(f, u);
            uint4 w = make_uint4(
                pk_bf16(f[0] * QSCALE, f[1] * QSCALE),
                pk_bf16(f[2] * QSCALE, f[3] * QSCALE),
                pk_bf16(f[4] * QSCALE, f[5] * QSCALE),
                pk_bf16(f[6] * QSCALE, f[7] * QSCALE));
            __builtin_memcpy(&bq[mi][ks], &w, 16);
        }
    }

    bf16x8 ones;
    #pragma unroll
    for (int e = 0; e < 8; e++) ones[e] = (__bf16)1.0f;

    f32x4 acc_o[2][4];
    f32x4 acc_l[2];
    #pragma unroll
    for (int mi = 0; mi < 2; mi++) {
        f32x4 z = {0.f, 0.f, 0.f, 0.f};
        acc_l[mi] = z;
        #pragma unroll
        for (int n = 0; n < 4; n++) acc_o[mi][n] = z;
    }

    // DMA lane geometry (XOR swizzle on the source side)
    const int lr = lane >> 3;                 // row-in-group 0..7
    const int cg = ((lane & 7) ^ lr) << 3;    // swizzled global chunk (elems)
    const ushort_t* kbase = &qkv[(size_t)(wave * 16 + lr) * QKV_O + K_COL + kvh * HD + cg];
    const size_t    kr8   = (size_t)8 * QKV_O;
    const ushort_t* vbase = &VtG[(size_t)(kvh * HD + wave * 16 + lr) * S_LEN + cg];
    const size_t    vr8   = (size_t)8 * S_LEN;

    const int nt = 32 - p;

    // ---- prologue: DMA tile 0 -> buffer 0 ----
    __builtin_amdgcn_global_load_lds(GLB(kbase),       LDSP(&Ks[0][wave * 16][0]),     16, 0, 0);
    __builtin_amdgcn_global_load_lds(GLB(kbase + kr8), LDSP(&Ks[0][wave * 16 + 8][0]), 16, 0, 0);
    __builtin_amdgcn_global_load_lds(GLB(vbase),       LDSP(&Vt[0][wave * 16][0]),     16, 0, 0);
    __builtin_amdgcn_global_load_lds(GLB(vbase + vr8), LDSP(&Vt[0][wave * 16 + 8][0]), 16, 0, 0);
    __syncthreads();

    for (int t = 0; t < nt; t++) {
        const int cur = t & 1, nxt = cur ^ 1;
        const int j0 = t * 64;

        // ---- DMA-prefetch tile t+1 -> alternate buffer ----
        if (t + 1 < nt) {
            const size_t kj = (size_t)(j0 + 64) * QKV_O;
            __builtin_amdgcn_global_load_lds(GLB(kbase + kj),           LDSP(&Ks[nxt][wave * 16][0]),     16, 0, 0);
            __builtin_amdgcn_global_load_lds(GLB(kbase + kj + kr8),     LDSP(&Ks[nxt][wave * 16 + 8][0]), 16, 0, 0);
            __builtin_amdgcn_global_load_lds(GLB(vbase + j0 + 64),      LDSP(&Vt[nxt][wave * 16][0]),     16, 0, 0);
            __builtin_amdgcn_global_load_lds(GLB(vbase + j0 + 64 + vr8),LDSP(&Vt[nxt][wave * 16 + 8][0]), 16, 0, 0);
        }

        const bool sact = (t <= p);          // shallow active (block-uniform)

        // ---- S^T = K·Q^T ----
        f32x4 st[2][4];
        #pragma unroll
        for (int mi = 0; mi < 2; mi++)
            #pragma unroll
            for (int nk = 0; nk < 4; nk++) {
                f32x4 z = {0.f, 0.f, 0.f, 0.f};
                st[mi][nk] = z;
            }
        #pragma unroll
        for (int ks = 0; ks < 2; ks++) {
            const int ca = (((ks << 2) + quad) ^ (l16 & 7)) << 3;
            bf16x8 ak[4];
            #pragma unroll
            for (int nk = 0; nk < 4; nk++)
                ak[nk] = *(const bf16x8*)&Ks[cur][nk * 16 + l16][ca];
            #pragma unroll
            for (int mi = 0; mi < 2; mi++) {
                if (mi == 1 && !sact) continue;
                #pragma unroll
                for (int nk = 0; nk < 4; nk++)
                    st[mi][nk] = __builtin_amdgcn_mfma_f32_16x16x32_bf16(
                        ak[nk], bq[mi][ks], st[mi][nk], 0, 0, 0);
            }
        }

        // ---- exp2 + causal mask, b64 P stores ----
        #pragma unroll
        for (int mi = 0; mi < 2; mi++) {
            if (mi == 1 && !sact) continue;
            const bool diag = (mi == 0) ? (t == nt - 1) : (t == p);
            const int qrow = ((mi == 0) ? rowbase0 : rowbase1) + l16;
            #pragma unroll
            for (int nk = 0; nk < 4; nk++) {
                const int kc0 = j0 + nk * 16 + quad * 4;
                float pv[4];
                #pragma unroll
                for (int r = 0; r < 4; r++) {
                    float e = exp2f(st[mi][nk][r]);
                    pv[r] = (diag && (kc0 + r > qrow)) ? 0.f : e;
                }
                uint2 w2 = make_uint2(pk_bf16(pv[0], pv[1]), pk_bf16(pv[2], pv[3]));
                *(uint2*)&Pl[wave][mi * 16 + l16][nk * 16 + quad * 4] = w2;
            }
        }

        // ---- l += P·1 ; O += P·V ----
        #pragma unroll
        for (int ksp = 0; ksp < 2; ksp++) {
            const int ca = (((ksp << 2) + quad) ^ (l16 & 7)) << 3;
            bf16x8 bv[4];
            #pragma unroll
            for (int nd = 0; nd < 4; nd++)
                bv[nd] = *(const bf16x8*)&Vt[cur][nd * 16 + l16][ca];
            #pragma unroll
            for (int mi = 0; mi < 2; mi++) {
                if (mi == 1 && !sact) continue;
                bf16x8 ap = *(const bf16x8*)&Pl[wave][mi * 16 + l16][ksp * 32 + quad * 8];
                acc_l[mi] = __builtin_amdgcn_mfma_f32_16x16x32_bf16(
                    ap, ones, acc_l[mi], 0, 0, 0);
                #pragma unroll
                for (int nd = 0; nd < 4; nd++)
                    acc_o[mi][nd] = __builtin_amdgcn_mfma_f32_16x16x32_bf16(
                        ap, bv[nd], acc_o[mi][nd], 0, 0, 0);
            }
        }
        __syncthreads();   // one barrier/tile; compiler drains vmcnt here
    }

    // ---- epilogue: O / l ----
    #pragma unroll
    for (int mi = 0; mi < 2; mi++) {
        const int rb = (mi == 0) ? rowbase0 : rowbase1;
        float inv[4];
        #pragma unroll
        for (int r = 0; r < 4; r++) inv[r] = 1.0f / acc_l[mi][r];
        #pragma unroll
        for (int nd = 0; nd < 4; nd++)
            #pragma unroll
            for (int r = 0; r < 4; r++) {
                int row = rb + quad * 4 + r;
                int col = h * HD + nd * 16 + l16;
                O[(size_t)row * (NQH * HD) + col] = f2bf(acc_o[mi][nd][r] * inv[r]);
            }
    }
}

// ---------------------------------------------------------------------------
extern "C" void kernel_launch(void* const* d_in, const int* in_sizes, int n_in,
                              void* d_out, int out_size, void* d_ws, size_t ws_size,
                              hipStream_t stream) {
    const float* x     = (const float*)d_in[0];  // [2048][2048] fp32
    const float* cosp  = (const float*)d_in[1];  // [2048][64]   fp32
    const float* sinp  = (const float*)d_in[2];  // [2048][64]   fp32
    const float* w_qkv = (const float*)d_in[3];  // [3072][2048] fp32
    const float* w_out = (const float*)d_in[4];  // [2048][2048] fp32
    float* out = (float*)d_out;                  // [2048][2048] fp32

    const size_t NQKV = (size_t)S_LEN * QKV_O;   // 6291456
    const size_t NH2  = (size_t)S_LEN * HID;     // 4194304
    const size_t NVT  = (size_t)(NKVH * HD) * S_LEN;  // 1048576
    const size_t need_old = 2 * (NQKV + NH2) * sizeof(ushort_t);        // 41.9 MB
    const size_t need_new = need_old + NVT * sizeof(ushort_t);          // 44.0 MB

    ushort_t* qkv = (ushort_t*)d_ws;             // bf16 [2048][3072]
    ushort_t* x_bf    = qkv + NQKV;
    ushort_t* attnO   = x_bf;                    // disjoint lifetimes
    ushort_t* wqkv_bf = x_bf + NH2;
    ushort_t* wout_bf = wqkv_bf + NQKV;
    ushort_t* VtG     = wout_bf + NH2;           // bf16 [512][2048]

    if (ws_size >= need_new) {
        convert3<<<XN8 / 256 + QN8 / 256 + ON8 / 256, 256, 0, stream>>>(
            x, w_qkv, w_out, x_bf, wqkv_bf, wout_bf);

        // 1) qkv(q,k w/ RoPE) + VtG(V^T) = x @ w_qkv^T
        dim3 g1(QKV_O / 128, S_LEN / 64);
        gemm_bk64<false, true, true><<<g1, 256, 0, stream>>>(
            x_bf, wqkv_bf, qkv, S_LEN, QKV_O, HID, cosp, sinp, VtG);

        // 2) causal GQA attention (64-row pairing, full DMA staging)
        attn_v6<<<16 * NQH, 256, 0, stream>>>(qkv, VtG, attnO);

        // 3) out = attnO @ w_out^T
        dim3 g2(HID / 128, S_LEN / 64);
        gemm_bk64<true, false, false><<<g2, 256, 0, stream>>>(
            attnO, wout_bf, out, S_LEN, HID, HID, nullptr, nullptr, nullptr);
    } else if (ws_size >= need_old) {
        convert3<<<XN8 / 256 + QN8 / 256 + ON8 / 256, 256, 0, stream>>>(
            x, w_qkv, w_out, x_bf, wqkv_bf, wout_bf);

        dim3 g1(QKV_O / 128, S_LEN / 64);
        gemm_bk64<false, true, false><<<g1, 256, 0, stream>>>(
            x_bf, wqkv_bf, qkv, S_LEN, QKV_O, HID, cosp, sinp, nullptr);

        attn_v5<<<16 * NQH, 256, 0, stream>>>(qkv, attnO);

        dim3 g2(HID / 128, S_LEN / 64);
        gemm_bk64<true, false, false><<<g2, 256, 0, stream>>>(
            attnO, wout_bf, out, S_LEN, HID, HID, nullptr, nullptr, nullptr);
    } else {
        ushort_t* attnO2 = qkv + NQKV;

        dim3 g1(QKV_O / 128, S_LEN / 128);
        gemm_bt<true, true, false><<<g1, 256, 0, stream>>>(x, w_qkv, qkv, S_LEN, QKV_O, HID);

        int rope_threads = S_LEN * (NQH + NKVH);
        rope_kernel<<<(rope_threads + 255) / 256, 256, 0, stream>>>(qkv, cosp, sinp);

        attn_v5<<<16 * NQH, 256, 0, stream>>>(qkv, attnO2);

        dim3 g2(HID / 128, S_LEN / 128);
        gemm_bt<false, true, true><<<g2, 256, 0, stream>>>(attnO2, w_out, out, S_LEN, HID, HID);
    }
}